// Round 15
// baseline (32.472 us; speedup 1.0000x reference)
//
#include <hip/hip_runtime.h>
#include <math.h>

#define TANFOV 1.0f

// AoS gaussian record: 3 x float4 (ORIGINAL gaussian order; depth order via
// the in-LDS perm rebuilt by the render kernel from rankpart)
//   [0] = (tz, -0.5*conA, -conB, -0.5*conC)
//   [1] = (mx, my, op(0 if invalid), 0)
//   [2] = (c0, c1, c2, 0)
#define REC   12     // floats per gaussian
#define CHG   256    // gaussians per depth chunk (== one wave's window)
#define SEG_L 256    // sort segment length (NJ = N/SEG_L = 8 partials)
#define MAXW  8      // max depth chunks / waves per render block
#define MAXN  (MAXW * CHG)   // 2048

// ---------------------------------------------------------------------------
// Kernel A: role-split fused launch (no data dependency between roles):
//   blocks [0, NB)           : preprocess 256 gaussians each
//   blocks [NB, NB + NB*NJ)  : sort partial-rank count (col, seg)
// Count computes tz directly from xyz+vm (6 flops) instead of depending on
// preprocess output -- this is what makes the fusion legal.
// ---------------------------------------------------------------------------
__global__ __launch_bounds__(256)
void pre_count_kernel(
    const float* __restrict__ xyz, const float* __restrict__ scaling,
    const float* __restrict__ rotation, const float* __restrict__ opacity,
    const float* __restrict__ fdc, const float* __restrict__ frest,
    const float* __restrict__ vm, const float* __restrict__ pm,
    const float* __restrict__ campos,
    const int* __restrict__ pH, const int* __restrict__ pW,
    float* __restrict__ pre, float4* __restrict__ bboxpre,
    int* __restrict__ rankpart, float* __restrict__ radii_out,
    int N, int NB, int NJ)
{
    __shared__ float s_fr[256 * 45];      // preprocess: frest staging (46 KB)
    const int tid = threadIdx.x;
    const int bid = blockIdx.x;

    if (bid >= NB) {
        // ================= role: sort partial-rank count =================
        float* s_tz = s_fr;               // alias (SEG_L floats used)
        int t = bid - NB;
        int col = t / NJ, seg = t - col * NJ;
        int base = seg * SEG_L;
        float c2 = vm[2], c6 = vm[6], c10 = vm[10], c14 = vm[14];
        if (tid < SEG_L) {
            int j = base + tid;
            s_tz[tid] = (j < N)
                ? xyz[j*3+0]*c2 + xyz[j*3+1]*c6 + xyz[j*3+2]*c10 + c14
                : 3.4e38f;
        }
        __syncthreads();

        int i = col * 256 + tid;
        if (i < N) {
            float key = xyz[i*3+0]*c2 + xyz[i*3+1]*c6 + xyz[i*3+2]*c10 + c14;
            int cnt = 0;
            #pragma unroll 8
            for (int j = 0; j < SEG_L; j += 4) {
                float4 v = *reinterpret_cast<float4*>(&s_tz[j]);
                cnt += (v.x < key) || (v.x == key && (base + j)     < i);
                cnt += (v.y < key) || (v.y == key && (base + j + 1) < i);
                cnt += (v.z < key) || (v.z == key && (base + j + 2) < i);
                cnt += (v.w < key) || (v.w == key && (base + j + 3) < i);
            }
            rankpart[seg * N + i] = cnt;
        }
        return;
    }

    // ================= role: preprocess =================
    int i0 = bid * 256;
    int cnt = N - i0; if (cnt > 256) cnt = 256;
    for (int t = tid; t < cnt * 45; t += 256)
        s_fr[t] = frest[(size_t)i0 * 45 + t];
    __syncthreads();

    int i = i0 + tid;
    if (i >= N) return;
    float H = (float)*pH, W = (float)*pW;

    float px_ = xyz[i*3+0], py_ = xyz[i*3+1], pz_ = xyz[i*3+2];
    float s0 = expf(scaling[i*3+0]), s1 = expf(scaling[i*3+1]), s2 = expf(scaling[i*3+2]);
    float op = 1.f / (1.f + expf(-opacity[i]));

    float qw = rotation[i*4+0], qx = rotation[i*4+1], qy = rotation[i*4+2], qz = rotation[i*4+3];
    float qn = fmaxf(sqrtf(qw*qw + qx*qx + qy*qy + qz*qz), 1e-12f);
    qw /= qn; qx /= qn; qy /= qn; qz /= qn;

    float R00 = 1.f - 2.f*(qy*qy + qz*qz), R01 = 2.f*(qx*qy - qw*qz), R02 = 2.f*(qx*qz + qw*qy);
    float R10 = 2.f*(qx*qy + qw*qz), R11 = 1.f - 2.f*(qx*qx + qz*qz), R12 = 2.f*(qy*qz - qw*qx);
    float R20 = 2.f*(qx*qz - qw*qy), R21 = 2.f*(qy*qz + qw*qx), R22 = 1.f - 2.f*(qx*qx + qy*qy);

    float M00 = R00*s0, M01 = R01*s1, M02 = R02*s2;
    float M10 = R10*s0, M11 = R11*s1, M12 = R12*s2;
    float M20 = R20*s0, M21 = R21*s1, M22 = R22*s2;

    float S00 = M00*M00 + M01*M01 + M02*M02;
    float S01 = M00*M10 + M01*M11 + M02*M12;
    float S02 = M00*M20 + M01*M21 + M02*M22;
    float S11 = M10*M10 + M11*M11 + M12*M12;
    float S12 = M10*M20 + M11*M21 + M12*M22;
    float S22 = M20*M20 + M21*M21 + M22*M22;

    float t0 = px_*vm[0] + py_*vm[4] + pz_*vm[8]  + vm[12];
    float t1 = px_*vm[1] + py_*vm[5] + pz_*vm[9]  + vm[13];
    float tz = px_*vm[2] + py_*vm[6] + pz_*vm[10] + vm[14];

    float fx = W / (2.f * TANFOV), fy = H / (2.f * TANFOV);
    float lim = 1.3f * TANFOV;
    float tzs = (fabsf(tz) > 1e-6f) ? tz : 1e-6f;
    float txz = fminf(fmaxf(t0 / tzs, -lim), lim) * tzs;
    float tyz = fminf(fmaxf(t1 / tzs, -lim), lim) * tzs;
    float J00 = fx / tzs, J02 = -fx * txz / (tzs * tzs);
    float J11 = fy / tzs, J12 = -fy * tyz / (tzs * tzs);

    float T00 = J00*vm[0] + J02*vm[2];
    float T01 = J00*vm[4] + J02*vm[6];
    float T02 = J00*vm[8] + J02*vm[10];
    float T10 = J11*vm[1] + J12*vm[2];
    float T11 = J11*vm[5] + J12*vm[6];
    float T12 = J11*vm[9] + J12*vm[10];

    float u0 = S00*T00 + S01*T01 + S02*T02;
    float u1 = S01*T00 + S11*T01 + S12*T02;
    float u2 = S02*T00 + S12*T01 + S22*T02;
    float v0 = S00*T10 + S01*T11 + S02*T12;
    float v1 = S01*T10 + S11*T11 + S12*T12;
    float v2 = S02*T10 + S12*T11 + S22*T12;
    float a  = T00*u0 + T01*u1 + T02*u2 + 0.3f;
    float b  = T10*u0 + T11*u1 + T12*u2;
    float c  = T10*v0 + T11*v1 + T12*v2 + 0.3f;

    float det = a*c - b*b;
    bool valid = (tz > 0.2f) && (det > 0.f);
    float inv_det = 1.f / ((det > 0.f) ? det : 1.f);
    float conA = c * inv_det, conB = -b * inv_det, conC = a * inv_det;
    float mid = 0.5f * (a + c);
    float lam = mid + sqrtf(fmaxf(mid*mid - det, 0.1f));
    radii_out[i] = valid ? ceilf(3.f * sqrtf(lam)) : 0.f;

    float h0 = px_*pm[0] + py_*pm[4] + pz_*pm[8]  + pm[12];
    float h1 = px_*pm[1] + py_*pm[5] + pz_*pm[9]  + pm[13];
    float h3 = px_*pm[3] + py_*pm[7] + pz_*pm[11] + pm[15];
    float pw = 1.f / (h3 + 1e-7f);
    float mx = ((h0*pw + 1.f) * W - 1.f) * 0.5f;
    float my = ((h1*pw + 1.f) * H - 1.f) * 0.5f;

    float ddx = px_ - campos[0], ddy = py_ - campos[1], ddz = pz_ - campos[2];
    float dn = fmaxf(sqrtf(ddx*ddx + ddy*ddy + ddz*ddz), 1e-12f);
    float x = ddx/dn, y = ddy/dn, z = ddz/dn;
    float xx = x*x, yy = y*y, zz = z*z, xy = x*y, yz = y*z, xz = x*z;

    float basis[16];
    basis[0]  = 0.28209479177387814f;
    basis[1]  = -0.4886025119029199f * y;
    basis[2]  =  0.4886025119029199f * z;
    basis[3]  = -0.4886025119029199f * x;
    basis[4]  =  1.0925484305920792f * xy;
    basis[5]  = -1.0925484305920792f * yz;
    basis[6]  =  0.31539156525252005f * (2.f*zz - xx - yy);
    basis[7]  = -1.0925484305920792f * xz;
    basis[8]  =  0.5462742152960396f * (xx - yy);
    basis[9]  = -0.5900435899266435f * y * (3.f*xx - yy);
    basis[10] =  2.890611442640554f  * xy * z;
    basis[11] = -0.4570457994644658f * y * (4.f*zz - xx - yy);
    basis[12] =  0.3731763325901154f * z * (2.f*zz - 3.f*xx - 3.f*yy);
    basis[13] = -0.4570457994644658f * x * (4.f*zz - xx - yy);
    basis[14] =  1.445305721320277f  * z * (xx - yy);
    basis[15] = -0.5900435899266435f * x * (xx - 3.f*yy);

    const float* fr = &s_fr[tid * 45];
    float col[3];
    #pragma unroll
    for (int ch = 0; ch < 3; ++ch) {
        float r = basis[0] * fdc[i*3 + ch];
        #pragma unroll
        for (int j = 1; j < 16; ++j)
            r += basis[j] * fr[(j-1)*3 + ch];
        col[ch] = fmaxf(r + 0.5f, 0.f);
    }

    float opv = valid ? op : 0.f;
    float4* rec = (float4*)(pre + (size_t)i * REC);
    rec[0] = make_float4(tz, -0.5f*conA, -conB, -0.5f*conC);
    rec[1] = make_float4(mx, my, opv, 0.f);
    rec[2] = make_float4(col[0], col[1], col[2], 0.f);

    float4 bb;
    if (opv > 1.f/255.f) {
        float Rr = 1.01f * sqrtf(2.f * logf(255.f * opv) * lam) + 1.f;
        bb = make_float4(mx - Rr, mx + Rr, my - Rr, my + Rr);
    } else {
        bb = make_float4(1e30f, -1e30f, 1e30f, -1e30f);   // empty
    }
    bboxpre[i] = bb;
}

// ---------------------------------------------------------------------------
// Kernel B: fused perm-rebuild + blend + combine. Block = one 8x8 pixel
// tile, G waves.
//  Step 0 (whole block): rebuild the depth permutation in LDS from rankpart:
//    thread t sums NJ=8 partials for gaussians t, t+512, ... (coalesced,
//    independent L2 loads) and scatters s_perm[rank] = i (bijective, no
//    atomics). One __syncthreads().  Replaces the scatter launch.
//  Then wave w owns depth chunk w: cull its 256-slot window vs the tile
//  (ballot-compact, depth order preserved), stage survivors in 64-record
//  batches to wave-private LDS, blend its 64 pixels into registers -- no
//  cross-wave sync. Finally one __syncthreads() and wave 0 combines the G
//  chunk partials per pixel front-to-back and writes color/depth/amap.
// ---------------------------------------------------------------------------
__global__ __launch_bounds__(512)
void blend_fused_kernel(const float4* __restrict__ grec,
                        const float4* __restrict__ bbox,
                        const int* __restrict__ rankpart,
                        const int* __restrict__ pW,
                        const float* __restrict__ bg,
                        float* __restrict__ out,
                        int N, int HW, int G, int NJ)
{
    __shared__ int    s_perm[MAXN];           // depth-order -> orig index
    __shared__ int    s_idx[MAXW][CHG];       // survivor orig-indices per wave
    __shared__ float4 s_rec[MAXW][3 * 64];    // staged records per wave
    __shared__ float  s_part[MAXW][5][64];    // per-wave partials

    const int tid = threadIdx.x;
    const int w = tid >> 6;                   // wave id == depth chunk id
    const int l = tid & 63;                   // lane id == pixel id in tile
    const int nthr = blockDim.x;

    // ---- Step 0: rebuild permutation from rank partials ----
    for (int i = tid; i < N; i += nthr) {
        int rank = 0;
        for (int s = 0; s < NJ; ++s) rank += rankpart[s * N + i];
        s_perm[rank] = i;
    }

    int W = *pW;
    int tilesX = W >> 3;
    int tileX = blockIdx.x % tilesX;
    int tileY = blockIdx.x / tilesX;
    int px = (tileX << 3) + (l & 7);
    int py = (tileY << 3) + (l >> 3);
    int pix = py * W + px;
    float fpx = (float)px, fpy = (float)py;
    float ftx0 = (float)(tileX << 3), ftx1 = ftx0 + 7.f;
    float fty0 = (float)(tileY << 3), fty1 = fty0 + 7.f;
    __syncthreads();

    // ---- cull chunk w: 4 rounds of 64, ballot-compact (depth order) ----
    int K = 0;
    int g0 = w * CHG;
    #pragma unroll
    for (int it = 0; it < CHG / 64; ++it) {
        int g = g0 + (it << 6) + l;
        bool hit = false; int orig = 0;
        if (g < N) {
            orig = s_perm[g];                // LDS read
            float4 bb = bbox[orig];          // gathered 16B load (L2)
            hit = (bb.x <= ftx1) && (bb.y >= ftx0) &&
                  (bb.z <= fty1) && (bb.w >= fty0);
        }
        unsigned long long m = __ballot(hit);
        if (hit) {
            int pos = __popcll(m & ((1ull << l) - 1ull));
            s_idx[w][K + pos] = orig;
        }
        K += __popcll(m);
    }

    // ---- blend chunk w for this wave's 64 pixels, in 64-record batches ----
    float T = 1.f, c0 = 0.f, c1 = 0.f, c2 = 0.f, d = 0.f;
    for (int b0 = 0; b0 < K; b0 += 64) {
        int nb = K - b0; if (nb > 64) nb = 64;
        for (int k = l; k < 3 * nb; k += 64) {
            int s = k / 3, e = k - 3 * s;
            s_rec[w][k] = grec[3 * s_idx[w][b0 + s] + e];
        }
        __builtin_amdgcn_wave_barrier();     // keep compiler from reordering
        for (int s = 0; s < nb; ++s) {
            float4 pA = s_rec[w][3*s+0];     // tz, a2, b2, c2
            float4 pB = s_rec[w][3*s+1];     // mx, my, op, -
            float4 pC = s_rec[w][3*s+2];     // rgb
            float dx = fpx - pB.x, dy = fpy - pB.y;
            float power = pA.y*dx*dx + pA.w*dy*dy + pA.z*dx*dy;
            float alpha = fminf(0.99f, pB.z * __expf(fminf(power, 0.f)));
            bool keep = (power <= 0.f) && (alpha >= 1.f/255.f);
            float aeff = keep ? alpha : 0.f;
            float wt = aeff * T;
            c0 = fmaf(wt, pC.x, c0);
            c1 = fmaf(wt, pC.y, c1);
            c2 = fmaf(wt, pC.z, c2);
            d  = fmaf(wt, pA.x, d);
            T  = T - aeff * T;
        }
        __builtin_amdgcn_wave_barrier();
    }

    s_part[w][0][l] = c0; s_part[w][1][l] = c1; s_part[w][2][l] = c2;
    s_part[w][3][l] = d;  s_part[w][4][l] = T;
    __syncthreads();

    // ---- combine: wave 0, one pixel per lane, front-to-back over chunks ----
    if (w == 0 && pix < HW) {
        float Tc = 1.f, f0 = 0.f, f1 = 0.f, f2 = 0.f, fd = 0.f;
        for (int k = 0; k < G; ++k) {
            f0 += Tc * s_part[k][0][l];
            f1 += Tc * s_part[k][1][l];
            f2 += Tc * s_part[k][2][l];
            fd += Tc * s_part[k][3][l];
            Tc *= s_part[k][4][l];
        }
        out[0*HW+pix] = f0 + Tc*bg[0];
        out[1*HW+pix] = f1 + Tc*bg[1];
        out[2*HW+pix] = f2 + Tc*bg[2];
        out[3*HW+pix] = fd;
        out[4*HW+pix] = 1.f - Tc;
    }
}

extern "C" void kernel_launch(void* const* d_in, const int* in_sizes, int n_in,
                              void* d_out, int out_size, void* d_ws, size_t ws_size,
                              hipStream_t stream) {
    const float* xyz      = (const float*)d_in[0];
    const float* scaling  = (const float*)d_in[1];
    const float* rotation = (const float*)d_in[2];
    const float* opacity  = (const float*)d_in[3];
    const float* fdc      = (const float*)d_in[4];
    const float* frest    = (const float*)d_in[5];
    const float* vm       = (const float*)d_in[6];
    const float* pm       = (const float*)d_in[7];
    const float* campos   = (const float*)d_in[8];
    const float* bg       = (const float*)d_in[9];
    const int*   pH       = (const int*)d_in[10];
    const int*   pW       = (const int*)d_in[11];

    int N  = in_sizes[0] / 3;
    int HW = (out_size - N) / 5;
    int G  = (N + CHG - 1) / CHG;       // 8 chunks (== waves per block)
    int NJ = (N + SEG_L - 1) / SEG_L;   // 8 segments
    int NB = (N + 255) / 256;           // 8 columns
    int NTILE = HW / 64;                // 256 8x8 tiles

    // ws layout:
    //   pre     : REC*N floats
    //   bboxpre : 4*N floats
    //   rankpart: NJ*N ints
    float*  ws       = (float*)d_ws;
    float*  pre      = ws;
    float4* bboxpre  = (float4*)(pre + (size_t)REC * N);
    int*    rankpart = (int*)(bboxpre + N);

    float* out   = (float*)d_out;
    float* radii = out + (size_t)5 * HW;

    // Kernel A: preprocess (blocks 0..NB-1) || count (blocks NB..NB+NB*NJ-1)
    pre_count_kernel<<<NB + NB * NJ, 256, 0, stream>>>(
        xyz, scaling, rotation, opacity, fdc, frest, vm, pm, campos, pH, pW,
        pre, bboxpre, rankpart, radii, N, NB, NJ);
    // Kernel B: fused perm-rebuild + per-tile blend + in-block combine
    blend_fused_kernel<<<NTILE, G * 64, 0, stream>>>(
        (const float4*)pre, bboxpre, rankpart, pW, bg, out, N, HW, G, NJ);
}

// Round 16
// 26.959 us; speedup vs baseline: 1.2045x; 1.2045x over previous
//
#include <hip/hip_runtime.h>
#include <math.h>

#define TANFOV 1.0f

// AoS gaussian record: 3 x float4 (ORIGINAL gaussian order; depth order via
// the in-LDS perm rebuilt by the render kernel from rankpart)
//   [0] = (tz, -0.5*conA, -conB, -0.5*conC)
//   [1] = (mx, my, op(0 if invalid), 0)
//   [2] = (c0, c1, c2, 0)
#define REC   12     // floats per gaussian
#define CHG   256    // gaussians per depth chunk (== one wave's window)
#define SEG_L 256    // sort segment length (NJ = N/SEG_L = 8 partials)
#define MAXW  8      // max depth chunks / waves per render block
#define MAXN  (MAXW * CHG)   // 2048

// ---------------------------------------------------------------------------
// Kernel A: role-split fused launch (no data dependency between roles):
//   blocks [0, NB)           : preprocess 256 gaussians each
//   blocks [NB, NB + NB*NJ)  : sort partial-rank count (col, seg)
// Count computes tz directly from xyz+vm (6 flops) instead of depending on
// preprocess output -- this is what makes the fusion legal.
// ---------------------------------------------------------------------------
__global__ __launch_bounds__(256)
void pre_count_kernel(
    const float* __restrict__ xyz, const float* __restrict__ scaling,
    const float* __restrict__ rotation, const float* __restrict__ opacity,
    const float* __restrict__ fdc, const float* __restrict__ frest,
    const float* __restrict__ vm, const float* __restrict__ pm,
    const float* __restrict__ campos,
    const int* __restrict__ pH, const int* __restrict__ pW,
    float* __restrict__ pre, float4* __restrict__ bboxpre,
    int* __restrict__ rankpart, float* __restrict__ radii_out,
    int N, int NB, int NJ)
{
    __shared__ float s_fr[256 * 45];      // preprocess: frest staging (46 KB)
    const int tid = threadIdx.x;
    const int bid = blockIdx.x;

    if (bid >= NB) {
        // ================= role: sort partial-rank count =================
        float* s_tz = s_fr;               // alias (SEG_L floats used)
        int t = bid - NB;
        int col = t / NJ, seg = t - col * NJ;
        int base = seg * SEG_L;
        float c2 = vm[2], c6 = vm[6], c10 = vm[10], c14 = vm[14];
        if (tid < SEG_L) {
            int j = base + tid;
            s_tz[tid] = (j < N)
                ? xyz[j*3+0]*c2 + xyz[j*3+1]*c6 + xyz[j*3+2]*c10 + c14
                : 3.4e38f;
        }
        __syncthreads();

        int i = col * 256 + tid;
        if (i < N) {
            float key = xyz[i*3+0]*c2 + xyz[i*3+1]*c6 + xyz[i*3+2]*c10 + c14;
            int cnt = 0;
            #pragma unroll 8
            for (int j = 0; j < SEG_L; j += 4) {
                float4 v = *reinterpret_cast<float4*>(&s_tz[j]);
                cnt += (v.x < key) || (v.x == key && (base + j)     < i);
                cnt += (v.y < key) || (v.y == key && (base + j + 1) < i);
                cnt += (v.z < key) || (v.z == key && (base + j + 2) < i);
                cnt += (v.w < key) || (v.w == key && (base + j + 3) < i);
            }
            rankpart[seg * N + i] = cnt;
        }
        return;
    }

    // ================= role: preprocess =================
    int i0 = bid * 256;
    int cnt = N - i0; if (cnt > 256) cnt = 256;
    for (int t = tid; t < cnt * 45; t += 256)
        s_fr[t] = frest[(size_t)i0 * 45 + t];
    __syncthreads();

    int i = i0 + tid;
    if (i >= N) return;
    float H = (float)*pH, W = (float)*pW;

    float px_ = xyz[i*3+0], py_ = xyz[i*3+1], pz_ = xyz[i*3+2];
    float s0 = expf(scaling[i*3+0]), s1 = expf(scaling[i*3+1]), s2 = expf(scaling[i*3+2]);
    float op = 1.f / (1.f + expf(-opacity[i]));

    float qw = rotation[i*4+0], qx = rotation[i*4+1], qy = rotation[i*4+2], qz = rotation[i*4+3];
    float qn = fmaxf(sqrtf(qw*qw + qx*qx + qy*qy + qz*qz), 1e-12f);
    qw /= qn; qx /= qn; qy /= qn; qz /= qn;

    float R00 = 1.f - 2.f*(qy*qy + qz*qz), R01 = 2.f*(qx*qy - qw*qz), R02 = 2.f*(qx*qz + qw*qy);
    float R10 = 2.f*(qx*qy + qw*qz), R11 = 1.f - 2.f*(qx*qx + qz*qz), R12 = 2.f*(qy*qz - qw*qx);
    float R20 = 2.f*(qx*qz - qw*qy), R21 = 2.f*(qy*qz + qw*qx), R22 = 1.f - 2.f*(qx*qx + qy*qy);

    float M00 = R00*s0, M01 = R01*s1, M02 = R02*s2;
    float M10 = R10*s0, M11 = R11*s1, M12 = R12*s2;
    float M20 = R20*s0, M21 = R21*s1, M22 = R22*s2;

    float S00 = M00*M00 + M01*M01 + M02*M02;
    float S01 = M00*M10 + M01*M11 + M02*M12;
    float S02 = M00*M20 + M01*M21 + M02*M22;
    float S11 = M10*M10 + M11*M11 + M12*M12;
    float S12 = M10*M20 + M11*M21 + M12*M22;
    float S22 = M20*M20 + M21*M21 + M22*M22;

    float t0 = px_*vm[0] + py_*vm[4] + pz_*vm[8]  + vm[12];
    float t1 = px_*vm[1] + py_*vm[5] + pz_*vm[9]  + vm[13];
    float tz = px_*vm[2] + py_*vm[6] + pz_*vm[10] + vm[14];

    float fx = W / (2.f * TANFOV), fy = H / (2.f * TANFOV);
    float lim = 1.3f * TANFOV;
    float tzs = (fabsf(tz) > 1e-6f) ? tz : 1e-6f;
    float txz = fminf(fmaxf(t0 / tzs, -lim), lim) * tzs;
    float tyz = fminf(fmaxf(t1 / tzs, -lim), lim) * tzs;
    float J00 = fx / tzs, J02 = -fx * txz / (tzs * tzs);
    float J11 = fy / tzs, J12 = -fy * tyz / (tzs * tzs);

    float T00 = J00*vm[0] + J02*vm[2];
    float T01 = J00*vm[4] + J02*vm[6];
    float T02 = J00*vm[8] + J02*vm[10];
    float T10 = J11*vm[1] + J12*vm[2];
    float T11 = J11*vm[5] + J12*vm[6];
    float T12 = J11*vm[9] + J12*vm[10];

    float u0 = S00*T00 + S01*T01 + S02*T02;
    float u1 = S01*T00 + S11*T01 + S12*T02;
    float u2 = S02*T00 + S12*T01 + S22*T02;
    float v0 = S00*T10 + S01*T11 + S02*T12;
    float v1 = S01*T10 + S11*T11 + S12*T12;
    float v2 = S02*T10 + S12*T11 + S22*T12;
    float a  = T00*u0 + T01*u1 + T02*u2 + 0.3f;
    float b  = T10*u0 + T11*u1 + T12*u2;
    float c  = T10*v0 + T11*v1 + T12*v2 + 0.3f;

    float det = a*c - b*b;
    bool valid = (tz > 0.2f) && (det > 0.f);
    float inv_det = 1.f / ((det > 0.f) ? det : 1.f);
    float conA = c * inv_det, conB = -b * inv_det, conC = a * inv_det;
    float mid = 0.5f * (a + c);
    float lam = mid + sqrtf(fmaxf(mid*mid - det, 0.1f));
    radii_out[i] = valid ? ceilf(3.f * sqrtf(lam)) : 0.f;

    float h0 = px_*pm[0] + py_*pm[4] + pz_*pm[8]  + pm[12];
    float h1 = px_*pm[1] + py_*pm[5] + pz_*pm[9]  + pm[13];
    float h3 = px_*pm[3] + py_*pm[7] + pz_*pm[11] + pm[15];
    float pw = 1.f / (h3 + 1e-7f);
    float mx = ((h0*pw + 1.f) * W - 1.f) * 0.5f;
    float my = ((h1*pw + 1.f) * H - 1.f) * 0.5f;

    float ddx = px_ - campos[0], ddy = py_ - campos[1], ddz = pz_ - campos[2];
    float dn = fmaxf(sqrtf(ddx*ddx + ddy*ddy + ddz*ddz), 1e-12f);
    float x = ddx/dn, y = ddy/dn, z = ddz/dn;
    float xx = x*x, yy = y*y, zz = z*z, xy = x*y, yz = y*z, xz = x*z;

    float basis[16];
    basis[0]  = 0.28209479177387814f;
    basis[1]  = -0.4886025119029199f * y;
    basis[2]  =  0.4886025119029199f * z;
    basis[3]  = -0.4886025119029199f * x;
    basis[4]  =  1.0925484305920792f * xy;
    basis[5]  = -1.0925484305920792f * yz;
    basis[6]  =  0.31539156525252005f * (2.f*zz - xx - yy);
    basis[7]  = -1.0925484305920792f * xz;
    basis[8]  =  0.5462742152960396f * (xx - yy);
    basis[9]  = -0.5900435899266435f * y * (3.f*xx - yy);
    basis[10] =  2.890611442640554f  * xy * z;
    basis[11] = -0.4570457994644658f * y * (4.f*zz - xx - yy);
    basis[12] =  0.3731763325901154f * z * (2.f*zz - 3.f*xx - 3.f*yy);
    basis[13] = -0.4570457994644658f * x * (4.f*zz - xx - yy);
    basis[14] =  1.445305721320277f  * z * (xx - yy);
    basis[15] = -0.5900435899266435f * x * (xx - 3.f*yy);

    const float* fr = &s_fr[tid * 45];
    float col[3];
    #pragma unroll
    for (int ch = 0; ch < 3; ++ch) {
        float r = basis[0] * fdc[i*3 + ch];
        #pragma unroll
        for (int j = 1; j < 16; ++j)
            r += basis[j] * fr[(j-1)*3 + ch];
        col[ch] = fmaxf(r + 0.5f, 0.f);
    }

    float opv = valid ? op : 0.f;
    float4* rec = (float4*)(pre + (size_t)i * REC);
    rec[0] = make_float4(tz, -0.5f*conA, -conB, -0.5f*conC);
    rec[1] = make_float4(mx, my, opv, 0.f);
    rec[2] = make_float4(col[0], col[1], col[2], 0.f);

    float4 bb;
    if (opv > 1.f/255.f) {
        float Rr = 1.01f * sqrtf(2.f * logf(255.f * opv) * lam) + 1.f;
        bb = make_float4(mx - Rr, mx + Rr, my - Rr, my + Rr);
    } else {
        bb = make_float4(1e30f, -1e30f, 1e30f, -1e30f);   // empty
    }
    bboxpre[i] = bb;
}

// ---------------------------------------------------------------------------
// Kernel B: fused perm-rebuild + blend + combine. Block = one 8x8 pixel
// tile, G waves.
//  Step 0: rebuild the depth permutation in LDS from rankpart. FULLY
//  UNROLLED for the N=2048/NJ=8/512-thread case: 32 INDEPENDENT coalesced
//  L2 loads per thread (no chained latency -- this was R15's mistake: the
//  runtime-bound loop serialized into a ~6K-cycle chain per block). Then
//  s_perm[rank] = i (bijective, no atomics), one __syncthreads().
//  Then wave w owns depth chunk w: cull its 256-slot window vs the tile
//  (ballot-compact, depth order preserved), stage survivors in 64-record
//  batches to wave-private LDS, blend its 64 pixels into registers -- no
//  cross-wave sync. Finally one __syncthreads() and wave 0 combines the G
//  chunk partials per pixel front-to-back and writes color/depth/amap.
// ---------------------------------------------------------------------------
__global__ __launch_bounds__(512)
void blend_fused_kernel(const float4* __restrict__ grec,
                        const float4* __restrict__ bbox,
                        const int* __restrict__ rankpart,
                        const int* __restrict__ pW,
                        const float* __restrict__ bg,
                        float* __restrict__ out,
                        int N, int HW, int G, int NJ)
{
    __shared__ int    s_perm[MAXN];           // depth-order -> orig index
    __shared__ int    s_idx[MAXW][CHG];       // survivor orig-indices per wave
    __shared__ float4 s_rec[MAXW][3 * 64];    // staged records per wave
    __shared__ float  s_part[MAXW][5][64];    // per-wave partials

    const int tid = threadIdx.x;
    const int w = tid >> 6;                   // wave id == depth chunk id
    const int l = tid & 63;                   // lane id == pixel id in tile
    const int nthr = blockDim.x;

    // ---- Step 0: rebuild permutation (latency-parallel fast path) ----
    if (N == MAXN && NJ == 8 && nthr == 512) {
        int r0 = 0, r1 = 0, r2 = 0, r3 = 0;
        #pragma unroll
        for (int s = 0; s < 8; ++s) {
            const int* rp = rankpart + s * MAXN;
            r0 += rp[tid];
            r1 += rp[tid + 512];
            r2 += rp[tid + 1024];
            r3 += rp[tid + 1536];
        }
        s_perm[r0] = tid;
        s_perm[r1] = tid + 512;
        s_perm[r2] = tid + 1024;
        s_perm[r3] = tid + 1536;
    } else {
        for (int i = tid; i < N; i += nthr) {
            int rank = 0;
            for (int s = 0; s < NJ; ++s) rank += rankpart[s * N + i];
            s_perm[rank] = i;
        }
    }

    int W = *pW;
    int tilesX = W >> 3;
    int tileX = blockIdx.x % tilesX;
    int tileY = blockIdx.x / tilesX;
    int px = (tileX << 3) + (l & 7);
    int py = (tileY << 3) + (l >> 3);
    int pix = py * W + px;
    float fpx = (float)px, fpy = (float)py;
    float ftx0 = (float)(tileX << 3), ftx1 = ftx0 + 7.f;
    float fty0 = (float)(tileY << 3), fty1 = fty0 + 7.f;
    __syncthreads();

    // ---- cull chunk w: 4 rounds of 64, ballot-compact (depth order) ----
    int K = 0;
    int g0 = w * CHG;
    #pragma unroll
    for (int it = 0; it < CHG / 64; ++it) {
        int g = g0 + (it << 6) + l;
        bool hit = false; int orig = 0;
        if (g < N) {
            orig = s_perm[g];                // LDS read
            float4 bb = bbox[orig];          // gathered 16B load (L2)
            hit = (bb.x <= ftx1) && (bb.y >= ftx0) &&
                  (bb.z <= fty1) && (bb.w >= fty0);
        }
        unsigned long long m = __ballot(hit);
        if (hit) {
            int pos = __popcll(m & ((1ull << l) - 1ull));
            s_idx[w][K + pos] = orig;
        }
        K += __popcll(m);
    }

    // ---- blend chunk w for this wave's 64 pixels, in 64-record batches ----
    float T = 1.f, c0 = 0.f, c1 = 0.f, c2 = 0.f, d = 0.f;
    for (int b0 = 0; b0 < K; b0 += 64) {
        int nb = K - b0; if (nb > 64) nb = 64;
        for (int k = l; k < 3 * nb; k += 64) {
            int s = k / 3, e = k - 3 * s;
            s_rec[w][k] = grec[3 * s_idx[w][b0 + s] + e];
        }
        __builtin_amdgcn_wave_barrier();     // keep compiler from reordering
        for (int s = 0; s < nb; ++s) {
            float4 pA = s_rec[w][3*s+0];     // tz, a2, b2, c2
            float4 pB = s_rec[w][3*s+1];     // mx, my, op, -
            float4 pC = s_rec[w][3*s+2];     // rgb
            float dx = fpx - pB.x, dy = fpy - pB.y;
            float power = pA.y*dx*dx + pA.w*dy*dy + pA.z*dx*dy;
            float alpha = fminf(0.99f, pB.z * __expf(fminf(power, 0.f)));
            bool keep = (power <= 0.f) && (alpha >= 1.f/255.f);
            float aeff = keep ? alpha : 0.f;
            float wt = aeff * T;
            c0 = fmaf(wt, pC.x, c0);
            c1 = fmaf(wt, pC.y, c1);
            c2 = fmaf(wt, pC.z, c2);
            d  = fmaf(wt, pA.x, d);
            T  = T - aeff * T;
        }
        __builtin_amdgcn_wave_barrier();
    }

    s_part[w][0][l] = c0; s_part[w][1][l] = c1; s_part[w][2][l] = c2;
    s_part[w][3][l] = d;  s_part[w][4][l] = T;
    __syncthreads();

    // ---- combine: wave 0, one pixel per lane, front-to-back over chunks ----
    if (w == 0 && pix < HW) {
        float Tc = 1.f, f0 = 0.f, f1 = 0.f, f2 = 0.f, fd = 0.f;
        for (int k = 0; k < G; ++k) {
            f0 += Tc * s_part[k][0][l];
            f1 += Tc * s_part[k][1][l];
            f2 += Tc * s_part[k][2][l];
            fd += Tc * s_part[k][3][l];
            Tc *= s_part[k][4][l];
        }
        out[0*HW+pix] = f0 + Tc*bg[0];
        out[1*HW+pix] = f1 + Tc*bg[1];
        out[2*HW+pix] = f2 + Tc*bg[2];
        out[3*HW+pix] = fd;
        out[4*HW+pix] = 1.f - Tc;
    }
}

extern "C" void kernel_launch(void* const* d_in, const int* in_sizes, int n_in,
                              void* d_out, int out_size, void* d_ws, size_t ws_size,
                              hipStream_t stream) {
    const float* xyz      = (const float*)d_in[0];
    const float* scaling  = (const float*)d_in[1];
    const float* rotation = (const float*)d_in[2];
    const float* opacity  = (const float*)d_in[3];
    const float* fdc      = (const float*)d_in[4];
    const float* frest    = (const float*)d_in[5];
    const float* vm       = (const float*)d_in[6];
    const float* pm       = (const float*)d_in[7];
    const float* campos   = (const float*)d_in[8];
    const float* bg       = (const float*)d_in[9];
    const int*   pH       = (const int*)d_in[10];
    const int*   pW       = (const int*)d_in[11];

    int N  = in_sizes[0] / 3;
    int HW = (out_size - N) / 5;
    int G  = (N + CHG - 1) / CHG;       // 8 chunks (== waves per block)
    int NJ = (N + SEG_L - 1) / SEG_L;   // 8 segments
    int NB = (N + 255) / 256;           // 8 columns
    int NTILE = HW / 64;                // 256 8x8 tiles

    // ws layout:
    //   pre     : REC*N floats
    //   bboxpre : 4*N floats
    //   rankpart: NJ*N ints
    float*  ws       = (float*)d_ws;
    float*  pre      = ws;
    float4* bboxpre  = (float4*)(pre + (size_t)REC * N);
    int*    rankpart = (int*)(bboxpre + N);

    float* out   = (float*)d_out;
    float* radii = out + (size_t)5 * HW;

    // Kernel A: preprocess (blocks 0..NB-1) || count (blocks NB..NB+NB*NJ-1)
    pre_count_kernel<<<NB + NB * NJ, 256, 0, stream>>>(
        xyz, scaling, rotation, opacity, fdc, frest, vm, pm, campos, pH, pW,
        pre, bboxpre, rankpart, radii, N, NB, NJ);
    // Kernel B: fused perm-rebuild (unrolled) + per-tile blend + combine
    blend_fused_kernel<<<NTILE, G * 64, 0, stream>>>(
        (const float4*)pre, bboxpre, rankpart, pW, bg, out, N, HW, G, NJ);
}